// Round 1
// baseline (1353.866 us; speedup 1.0000x reference)
//
#include <hip/hip_runtime.h>
#include <hip/hip_bf16.h>

typedef unsigned short u16;
typedef __bf16 bf16x8 __attribute__((ext_vector_type(8)));
typedef float f32x4 __attribute__((ext_vector_type(4)));
typedef u16 u16x8 __attribute__((ext_vector_type(8)));

// ---------- helpers ----------
__device__ __forceinline__ float bf2f(u16 u) {
    unsigned x = ((unsigned)u) << 16;
    return __builtin_bit_cast(float, x);
}
__device__ __forceinline__ u16 f2bf(float f) {  // round-to-nearest-even
    unsigned x = __builtin_bit_cast(unsigned, f);
    unsigned r = (x + 0x7fffu + ((x >> 16) & 1u)) >> 16;
    return (u16)r;
}
__device__ __forceinline__ float sigm(float x) { return 1.f / (1.f + __expf(-x)); }
__device__ __forceinline__ float tanh_fast(float x) { return 1.f - 2.f / (1.f + __expf(2.f * x)); }

// ---------- weight concat + fp32->bf16 convert ----------
__global__ void convw_kernel(const float* __restrict__ wf, const float* __restrict__ wr,
                             u16* __restrict__ out, int half_rows, int K) {
    int idx = blockIdx.x * 256 + threadIdx.x;
    int total = 2 * half_rows * K;
    if (idx >= total) return;
    int n = idx / K, k = idx - n * K;
    float v = (n < half_rows) ? wf[(size_t)n * K + k] : wr[(size_t)(n - half_rows) * K + k];
    out[idx] = f2bf(v);
}

// ---------- bf16 MFMA GEMM, C = A(MxK) * B^T (B is NxK row-major), C bf16 ----------
template <bool AF32>
__global__ __launch_bounds__(256, 2) void gemm_bf16_bt(const void* __restrict__ Av,
                                                       const u16* __restrict__ B,
                                                       u16* __restrict__ C,
                                                       int M, int N, int K) {
    __shared__ __align__(16) u16 As[128 * 40];  // pad 32->40 elems: stride 80B kills bank conflicts
    __shared__ __align__(16) u16 Bs[128 * 40];
    const int tid = threadIdx.x;
    const int n0 = blockIdx.x * 128, m0 = blockIdx.y * 128;
    const int srow = tid >> 1, shalf = tid & 1;
    const int lane = tid & 63, wv = tid >> 6;
    const int wm = wv >> 1, wn = wv & 1;
    const int frow = lane & 15, fko = (lane >> 4) * 8;
    f32x4 acc[4][4] = {};
    const int nk = K >> 5;
    for (int kt = 0; kt < nk; ++kt) {
        u16x8 a0, a1;
        if (AF32) {
            const float* ap = (const float*)Av + (size_t)(m0 + srow) * K + kt * 32 + shalf * 16;
            f32x4 f0 = *(const f32x4*)(ap);
            f32x4 f1 = *(const f32x4*)(ap + 4);
            f32x4 f2 = *(const f32x4*)(ap + 8);
            f32x4 f3 = *(const f32x4*)(ap + 12);
#pragma unroll
            for (int x = 0; x < 4; x++) {
                a0[x] = f2bf(f0[x]); a0[4 + x] = f2bf(f1[x]);
                a1[x] = f2bf(f2[x]); a1[4 + x] = f2bf(f3[x]);
            }
        } else {
            const u16* ap = (const u16*)Av + (size_t)(m0 + srow) * K + kt * 32 + shalf * 16;
            a0 = *(const u16x8*)(ap);
            a1 = *(const u16x8*)(ap + 8);
        }
        const u16* bp = B + (size_t)(n0 + srow) * K + kt * 32 + shalf * 16;
        u16x8 b0 = *(const u16x8*)(bp);
        u16x8 b1 = *(const u16x8*)(bp + 8);
        __syncthreads();  // previous iter's LDS readers done
        *(u16x8*)&As[srow * 40 + shalf * 16] = a0;
        *(u16x8*)&As[srow * 40 + shalf * 16 + 8] = a1;
        *(u16x8*)&Bs[srow * 40 + shalf * 16] = b0;
        *(u16x8*)&Bs[srow * 40 + shalf * 16 + 8] = b1;
        __syncthreads();
        bf16x8 af[4], bfr[4];
#pragma unroll
        for (int mi = 0; mi < 4; mi++)
            af[mi] = *(const bf16x8*)&As[(wm * 64 + mi * 16 + frow) * 40 + fko];
#pragma unroll
        for (int ni = 0; ni < 4; ni++)
            bfr[ni] = *(const bf16x8*)&Bs[(wn * 64 + ni * 16 + frow) * 40 + fko];
#pragma unroll
        for (int mi = 0; mi < 4; mi++)
#pragma unroll
            for (int ni = 0; ni < 4; ni++)
                acc[mi][ni] = __builtin_amdgcn_mfma_f32_16x16x32_bf16(af[mi], bfr[ni], acc[mi][ni], 0, 0, 0);
    }
    // epilogue: C/D layout col=lane&15, row=(lane>>4)*4+reg (m89-verified)
#pragma unroll
    for (int mi = 0; mi < 4; mi++)
#pragma unroll
        for (int ni = 0; ni < 4; ni++)
#pragma unroll
            for (int r = 0; r < 4; r++) {
                int row = m0 + wm * 64 + mi * 16 + (lane >> 4) * 4 + r;
                int col = n0 + wn * 64 + ni * 16 + (lane & 15);
                C[(size_t)row * N + col] = f2bf(acc[mi][ni][r]);
            }
}

// ---------- LSTM recurrence: one block per (batch, direction), W_hh in VGPRs ----------
// xproj: [b*512+t][1024] bf16 (cols d*512+g), hout: [b*512+t][256] bf16 (cols d*128+j)
__global__ __launch_bounds__(512, 2) void lstm_kernel(const u16* __restrict__ xproj,
                                                      const float* __restrict__ whh_f,
                                                      const float* __restrict__ whh_r,
                                                      const float* __restrict__ bih_f,
                                                      const float* __restrict__ bhh_f,
                                                      const float* __restrict__ bih_r,
                                                      const float* __restrict__ bhh_r,
                                                      u16* __restrict__ hout) {
    const int b = blockIdx.x, d = blockIdx.y;
    const int g = threadIdx.x;  // gate row 0..511
    const float* whh = d ? whh_r : whh_f;
    f32x4 w[32];
    const f32x4* wrow = (const f32x4*)(whh + (size_t)g * 128);
#pragma unroll
    for (int i = 0; i < 32; i++) w[i] = wrow[i];
    float bsum = (d ? bih_r[g] : bih_f[g]) + (d ? bhh_r[g] : bhh_f[g]);
    __shared__ __align__(16) float h_lds[128];
    __shared__ float glds[512];
    if (g < 128) h_lds[g] = 0.f;
    float c = 0.f;
    __syncthreads();
    const u16* xp = xproj + (size_t)b * 512 * 1024 + (size_t)d * 512 + g;
    for (int s = 0; s < 512; ++s) {
        const int tt = d ? (511 - s) : s;
        float gbase = bsum + bf2f(xp[(size_t)tt * 1024]);
        float a0 = 0.f, a1 = 0.f, a2 = 0.f, a3 = 0.f;
        const f32x4* h4 = (const f32x4*)h_lds;
#pragma unroll
        for (int i = 0; i < 32; i++) {
            f32x4 hv = h4[i];  // wave-uniform address -> LDS broadcast, conflict-free
            a0 = fmaf(w[i][0], hv[0], a0);
            a1 = fmaf(w[i][1], hv[1], a1);
            a2 = fmaf(w[i][2], hv[2], a2);
            a3 = fmaf(w[i][3], hv[3], a3);
        }
        glds[g] = gbase + ((a0 + a1) + (a2 + a3));
        __syncthreads();
        if (g < 128) {
            float gi = glds[g], gf = glds[g + 128], gg = glds[g + 256], go = glds[g + 384];
            c = sigm(gf) * c + sigm(gi) * tanh_fast(gg);
            float h = sigm(go) * tanh_fast(c);
            h_lds[g] = h;
            hout[((size_t)b * 512 + tt) * 256 + (size_t)d * 128 + g] = f2bf(h);
        }
        __syncthreads();
    }
}

// ---------- emissions: em[(t*64+b)*16+k] = h1(row b*512+t) . linear_w[k] + linear_b[k] ----------
__global__ __launch_bounds__(256) void em_kernel(const u16* __restrict__ h1,
                                                 const float* __restrict__ lw,
                                                 const float* __restrict__ lb,
                                                 float* __restrict__ em) {
    __shared__ float w[11 * 256];
    for (int i = threadIdx.x; i < 11 * 256; i += 256) w[i] = lw[i];
    __syncthreads();
    int r = blockIdx.x * 256 + threadIdx.x;
    const u16x8* hp = (const u16x8*)(h1 + (size_t)r * 256);
    float acc[11];
#pragma unroll
    for (int j = 0; j < 11; j++) acc[j] = lb[j];
    for (int kc = 0; kc < 32; ++kc) {
        u16x8 hv = hp[kc];
        float hf[8];
#pragma unroll
        for (int x = 0; x < 8; x++) hf[x] = bf2f(hv[x]);
#pragma unroll
        for (int x = 0; x < 8; x++)
#pragma unroll
            for (int j = 0; j < 11; j++) acc[j] = fmaf(hf[x], w[j * 256 + kc * 8 + x], acc[j]);
    }
    int b = r >> 9, t = r & 511;
    float* o = em + ((size_t)t * 64 + b) * 16;
#pragma unroll
    for (int j = 0; j < 11; j++) o[j] = acc[j];
}

// ---------- CRF: numerator (t-parallel) + denominator (forward scan), 4 batches/block ----------
__global__ __launch_bounds__(64) void crf_kernel(const float* __restrict__ em,
                                                 const int* __restrict__ tags,
                                                 const float* __restrict__ start_trans,
                                                 const float* __restrict__ end_trans,
                                                 const float* __restrict__ trans,
                                                 float* __restrict__ pb) {
    const int lane = threadIdx.x;
    const int seg = lane >> 4, kp = lane & 15;
    const int kpc = kp < 11 ? kp : 10;  // clamp: inactive lanes compute a duplicate valid chain
    const int b = blockIdx.x * 4 + seg;
    const int* tg = tags + (size_t)b * 512;
    // numerator: all 16 lanes of the segment sum strided t
    float num = 0.f;
    for (int t = kp; t < 512; t += 16) {
        int cur = tg[t];
        float e = em[((size_t)t * 64 + b) * 16 + cur];
        float tr = (t == 0) ? start_trans[cur] : trans[tg[t - 1] * 11 + cur];
        num += e + tr;
    }
#pragma unroll
    for (int off = 8; off >= 1; off >>= 1) num += __shfl_down(num, off, 16);
    // denominator: lane kpc holds state k'=kpc; shfl-gather within 16-lane segment
    float trcol[11];
#pragma unroll
    for (int k = 0; k < 11; k++) trcol[k] = trans[k * 11 + kpc];
    float s = start_trans[kpc] + em[(size_t)b * 16 + kpc];
    for (int t = 1; t < 512; ++t) {
        float v[11], m = -1e30f;
#pragma unroll
        for (int k = 0; k < 11; k++) {
            v[k] = __shfl(s, k, 16) + trcol[k];
            m = fmaxf(m, v[k]);
        }
        float sum = 0.f;
#pragma unroll
        for (int k = 0; k < 11; k++) sum += __expf(v[k] - m);
        s = m + __logf(sum) + em[((size_t)t * 64 + b) * 16 + kpc];
    }
    float u = s + end_trans[kpc];
    float m2 = -1e30f, vv[11];
#pragma unroll
    for (int k = 0; k < 11; k++) {
        vv[k] = __shfl(u, k, 16);
        m2 = fmaxf(m2, vv[k]);
    }
    float s2 = 0.f;
#pragma unroll
    for (int k = 0; k < 11; k++) s2 += __expf(vv[k] - m2);
    float den = m2 + __logf(s2);
    if (kp == 0) {
        float numt = num + end_trans[tg[511]];
        pb[b] = numt - den;
    }
}

__global__ __launch_bounds__(64) void final_kernel(const float* __restrict__ pb, float* __restrict__ out) {
    float v = pb[threadIdx.x];
#pragma unroll
    for (int off = 32; off >= 1; off >>= 1) v += __shfl_down(v, off, 64);
    if (threadIdx.x == 0) out[0] = -(v / 64.f);
}

// ---------- launch ----------
extern "C" void kernel_launch(void* const* d_in, const int* in_sizes, int n_in,
                              void* d_out, int out_size, void* d_ws, size_t ws_size,
                              hipStream_t stream) {
    const float* embeds = (const float*)d_in[0];
    const int* tags = (const int*)d_in[1];
    // d_in[2] = mask: all-ones by construction, ignored
    const float* wih0f = (const float*)d_in[3];
    const float* whh0f = (const float*)d_in[4];
    const float* bih0f = (const float*)d_in[5];
    const float* bhh0f = (const float*)d_in[6];
    const float* wih0r = (const float*)d_in[7];
    const float* whh0r = (const float*)d_in[8];
    const float* bih0r = (const float*)d_in[9];
    const float* bhh0r = (const float*)d_in[10];
    const float* wih1f = (const float*)d_in[11];
    const float* whh1f = (const float*)d_in[12];
    const float* bih1f = (const float*)d_in[13];
    const float* bhh1f = (const float*)d_in[14];
    const float* wih1r = (const float*)d_in[15];
    const float* whh1r = (const float*)d_in[16];
    const float* bih1r = (const float*)d_in[17];
    const float* bhh1r = (const float*)d_in[18];
    const float* lw = (const float*)d_in[19];
    const float* lb = (const float*)d_in[20];
    const float* st = (const float*)d_in[21];
    const float* et = (const float*)d_in[22];
    const float* tr = (const float*)d_in[23];
    float* out = (float*)d_out;

    char* ws = (char*)d_ws;
    u16* xproj = (u16*)(ws + 0);            // 32768*1024*2 = 64MB (reused by both layers)
    u16* h0 = (u16*)(ws + 67108864);        // 16MB
    u16* h1 = (u16*)(ws + 83886080);        // 16MB
    float* em = (float*)(ws + 100663296);   // 512*64*16*4 = 2MB
    u16* w0c = (u16*)(ws + 102760448);      // 1024*768*2
    u16* w1c = (u16*)(ws + 104333312);      // 1024*256*2
    float* pb = (float*)(ws + 104857600);   // 64*4

    // weight concat/convert
    convw_kernel<<<3072, 256, 0, stream>>>(wih0f, wih0r, w0c, 512, 768);
    convw_kernel<<<1024, 256, 0, stream>>>(wih1f, wih1r, w1c, 512, 256);
    // layer 0: input projection + recurrence
    gemm_bf16_bt<true><<<dim3(8, 256), 256, 0, stream>>>(embeds, w0c, xproj, 32768, 1024, 768);
    lstm_kernel<<<dim3(64, 2), 512, 0, stream>>>(xproj, whh0f, whh0r, bih0f, bhh0f, bih0r, bhh0r, h0);
    // layer 1
    gemm_bf16_bt<false><<<dim3(8, 256), 256, 0, stream>>>(h0, w1c, xproj, 32768, 1024, 256);
    lstm_kernel<<<dim3(64, 2), 512, 0, stream>>>(xproj, whh1f, whh1r, bih1f, bhh1f, bih1r, bhh1r, h1);
    // emissions + CRF
    em_kernel<<<128, 256, 0, stream>>>(h1, lw, lb, em);
    crf_kernel<<<16, 64, 0, stream>>>(em, tags, st, et, tr, pb);
    final_kernel<<<1, 64, 0, stream>>>(pb, out);
}

// Round 2
// 1239.000 us; speedup vs baseline: 1.0927x; 1.0927x over previous
//
#include <hip/hip_runtime.h>
#include <hip/hip_bf16.h>

typedef unsigned short u16;
typedef __bf16 bf16x8 __attribute__((ext_vector_type(8)));
typedef float f32x4 __attribute__((ext_vector_type(4)));
typedef u16 u16x8 __attribute__((ext_vector_type(8)));

// ---------- helpers ----------
__device__ __forceinline__ float bf2f(u16 u) {
    unsigned x = ((unsigned)u) << 16;
    return __builtin_bit_cast(float, x);
}
__device__ __forceinline__ u16 f2bf(float f) {  // round-to-nearest-even
    unsigned x = __builtin_bit_cast(unsigned, f);
    unsigned r = (x + 0x7fffu + ((x >> 16) & 1u)) >> 16;
    return (u16)r;
}
__device__ __forceinline__ float sigm(float x) {
    return __builtin_amdgcn_rcpf(1.f + __expf(-x));
}
__device__ __forceinline__ float tanh_fast(float x) {
    return 1.f - 2.f * __builtin_amdgcn_rcpf(1.f + __expf(2.f * x));
}

// ---------- weight concat + fp32->bf16 convert ----------
__global__ void convw_kernel(const float* __restrict__ wf, const float* __restrict__ wr,
                             u16* __restrict__ out, int half_rows, int K) {
    int idx = blockIdx.x * 256 + threadIdx.x;
    int total = 2 * half_rows * K;
    if (idx >= total) return;
    int n = idx / K, k = idx - n * K;
    float v = (n < half_rows) ? wf[(size_t)n * K + k] : wr[(size_t)(n - half_rows) * K + k];
    out[idx] = f2bf(v);
}

// ---------- bf16 MFMA GEMM, C = A(MxK) * B^T (B is NxK row-major), C bf16 ----------
template <bool AF32>
__global__ __launch_bounds__(256, 2) void gemm_bf16_bt(const void* __restrict__ Av,
                                                       const u16* __restrict__ B,
                                                       u16* __restrict__ C,
                                                       int M, int N, int K) {
    __shared__ __align__(16) u16 As[128 * 40];
    __shared__ __align__(16) u16 Bs[128 * 40];
    const int tid = threadIdx.x;
    const int n0 = blockIdx.x * 128, m0 = blockIdx.y * 128;
    const int srow = tid >> 1, shalf = tid & 1;
    const int lane = tid & 63, wv = tid >> 6;
    const int wm = wv >> 1, wn = wv & 1;
    const int frow = lane & 15, fko = (lane >> 4) * 8;
    f32x4 acc[4][4] = {};
    const int nk = K >> 5;
    for (int kt = 0; kt < nk; ++kt) {
        u16x8 a0, a1;
        if (AF32) {
            const float* ap = (const float*)Av + (size_t)(m0 + srow) * K + kt * 32 + shalf * 16;
            f32x4 f0 = *(const f32x4*)(ap);
            f32x4 f1 = *(const f32x4*)(ap + 4);
            f32x4 f2 = *(const f32x4*)(ap + 8);
            f32x4 f3 = *(const f32x4*)(ap + 12);
#pragma unroll
            for (int x = 0; x < 4; x++) {
                a0[x] = f2bf(f0[x]); a0[4 + x] = f2bf(f1[x]);
                a1[x] = f2bf(f2[x]); a1[4 + x] = f2bf(f3[x]);
            }
        } else {
            const u16* ap = (const u16*)Av + (size_t)(m0 + srow) * K + kt * 32 + shalf * 16;
            a0 = *(const u16x8*)(ap);
            a1 = *(const u16x8*)(ap + 8);
        }
        const u16* bp = B + (size_t)(n0 + srow) * K + kt * 32 + shalf * 16;
        u16x8 b0 = *(const u16x8*)(bp);
        u16x8 b1 = *(const u16x8*)(bp + 8);
        __syncthreads();
        *(u16x8*)&As[srow * 40 + shalf * 16] = a0;
        *(u16x8*)&As[srow * 40 + shalf * 16 + 8] = a1;
        *(u16x8*)&Bs[srow * 40 + shalf * 16] = b0;
        *(u16x8*)&Bs[srow * 40 + shalf * 16 + 8] = b1;
        __syncthreads();
        bf16x8 af[4], bfr[4];
#pragma unroll
        for (int mi = 0; mi < 4; mi++)
            af[mi] = *(const bf16x8*)&As[(wm * 64 + mi * 16 + frow) * 40 + fko];
#pragma unroll
        for (int ni = 0; ni < 4; ni++)
            bfr[ni] = *(const bf16x8*)&Bs[(wn * 64 + ni * 16 + frow) * 40 + fko];
#pragma unroll
        for (int mi = 0; mi < 4; mi++)
#pragma unroll
            for (int ni = 0; ni < 4; ni++)
                acc[mi][ni] = __builtin_amdgcn_mfma_f32_16x16x32_bf16(af[mi], bfr[ni], acc[mi][ni], 0, 0, 0);
    }
#pragma unroll
    for (int mi = 0; mi < 4; mi++)
#pragma unroll
        for (int ni = 0; ni < 4; ni++)
#pragma unroll
            for (int r = 0; r < 4; r++) {
                int row = m0 + wm * 64 + mi * 16 + (lane >> 4) * 4 + r;
                int col = n0 + wn * 64 + ni * 16 + (lane & 15);
                C[(size_t)row * N + col] = f2bf(acc[mi][ni][r]);
            }
}

// ---------- LSTM recurrence via MFMA: block = 2 batches x 1 direction ----------
// xproj: [b*512+t][1024] bf16 (cols d*512+g), W_hh held as bf16 B-frags in VGPRs.
// Per step: h-tile(16x128, rows 0-1 valid) from LDS -> 32 MFMA/wave -> shfl
// redistribute -> 1 c-val/lane pointwise -> h to LDS(double-buffered) + hout.
__global__ __launch_bounds__(256, 1) void lstm_mfma(const u16* __restrict__ xproj,
                                                    const float* __restrict__ whh_f,
                                                    const float* __restrict__ whh_r,
                                                    const float* __restrict__ bih_f,
                                                    const float* __restrict__ bhh_f,
                                                    const float* __restrict__ bih_r,
                                                    const float* __restrict__ bhh_r,
                                                    u16* __restrict__ hout) {
    const int p = blockIdx.x;  // batch pair: batches 2p, 2p+1
    const int d = blockIdx.y;
    const int tid = threadIdx.x;
    const int w = tid >> 6, l = tid & 63;
    const float* whh = d ? whh_r : whh_f;
    const float* bih = d ? bih_r : bih_f;
    const float* bhh = d ? bhh_r : bhh_f;

    // B-fragments: tile k -> gates [(w+4k)*16, +16), gt=k>>1, jg=k&1
    bf16x8 bf[8][4];
#pragma unroll
    for (int k = 0; k < 8; ++k) {
        const float* wr = whh + (size_t)((w + 4 * k) * 16 + (l & 15)) * 128;
#pragma unroll
        for (int c = 0; c < 4; ++c) {
            f32x4 x0 = *(const f32x4*)(wr + c * 32 + (l >> 4) * 8);
            f32x4 x1 = *(const f32x4*)(wr + c * 32 + (l >> 4) * 8 + 4);
            u16x8 t;
#pragma unroll
            for (int x = 0; x < 4; x++) { t[x] = f2bf(x0[x]); t[4 + x] = f2bf(x1[x]); }
            bf[k][c] = __builtin_bit_cast(bf16x8, t);
        }
    }

    // dst-lane assignment: b = l>>5, jg = (l>>4)&1, jcol = l&15
    const int jcol = l & 15, jg = (l >> 4) & 1, b = l >> 5;
    const int j = jg * 64 + w * 16 + jcol;
    float bias[4];
#pragma unroll
    for (int gt = 0; gt < 4; gt++) bias[gt] = bih[gt * 128 + j] + bhh[gt * 128 + j];

    __shared__ __align__(16) u16 h_lds[2][16 * 136];  // +8 u16 pad: conflict-free reads
    for (int i = tid; i < 2 * 16 * 136; i += 256) ((u16*)h_lds)[i] = 0;

    const u16* xb = xproj + (size_t)(2 * p + b) * 512 * 1024 + (size_t)d * 512 + j;
    u16 xv[4];
    {
        const int tt0 = d ? 511 : 0;
#pragma unroll
        for (int gt = 0; gt < 4; gt++) xv[gt] = xb[(size_t)tt0 * 1024 + gt * 128];
    }
    float c_state = 0.f;
    u16* ho = hout + (size_t)(2 * p + b) * 512 * 256 + (size_t)d * 128 + j;
    int cur = 0;
    __syncthreads();

    for (int s = 0; s < 512; ++s) {
        const int tt = d ? (511 - s) : s;
        // A-fragments from current h buffer
        bf16x8 af[4];
#pragma unroll
        for (int c = 0; c < 4; ++c)
            af[c] = *(const bf16x8*)&h_lds[cur][(l & 15) * 136 + c * 32 + (l >> 4) * 8];
        f32x4 acc[8];
#pragma unroll
        for (int k = 0; k < 8; ++k)
            acc[k] = __builtin_amdgcn_mfma_f32_16x16x32_bf16(af[0], bf[k][0], (f32x4){0.f, 0.f, 0.f, 0.f}, 0, 0, 0);
#pragma unroll
        for (int c = 1; c < 4; ++c)
#pragma unroll
            for (int k = 0; k < 8; ++k)
                acc[k] = __builtin_amdgcn_mfma_f32_16x16x32_bf16(af[c], bf[k][c], acc[k], 0, 0, 0);
        // redistribute: src lane jcol holds (row=b in r, col=jcol); gather i,f,g,o per (b,j)
        float gval[4];
#pragma unroll
        for (int gt = 0; gt < 4; gt++) {
            float x00 = __shfl(acc[2 * gt][0], jcol, 64);      // jg=0,b=0
            float x10 = __shfl(acc[2 * gt + 1][0], jcol, 64);  // jg=1,b=0
            float x01 = __shfl(acc[2 * gt][1], jcol, 64);      // jg=0,b=1
            float x11 = __shfl(acc[2 * gt + 1][1], jcol, 64);  // jg=1,b=1
            float xa = jg ? x10 : x00;
            float xc = jg ? x11 : x01;
            gval[gt] = (b ? xc : xa) + bf2f(xv[gt]) + bias[gt];
        }
        // prefetch next step's xproj (hidden under pointwise + barrier + next MFMA)
        {
            const int s2 = (s + 1) & 511;
            const int tt2 = d ? (511 - s2) : s2;
#pragma unroll
            for (int gt = 0; gt < 4; gt++) xv[gt] = xb[(size_t)tt2 * 1024 + gt * 128];
        }
        // pointwise (1 c-val per lane)
        float ip = sigm(gval[0]), fp = sigm(gval[1]);
        float tg = tanh_fast(gval[2]), op = sigm(gval[3]);
        c_state = fp * c_state + ip * tg;
        float h = op * tanh_fast(c_state);
        u16 hb = f2bf(h);
        h_lds[cur ^ 1][b * 136 + j] = hb;
        ho[(size_t)tt * 256] = hb;
        __syncthreads();
        cur ^= 1;
    }
}

// ---------- emissions ----------
__global__ __launch_bounds__(256) void em_kernel(const u16* __restrict__ h1,
                                                 const float* __restrict__ lw,
                                                 const float* __restrict__ lb,
                                                 float* __restrict__ em) {
    __shared__ float w[11 * 256];
    for (int i = threadIdx.x; i < 11 * 256; i += 256) w[i] = lw[i];
    __syncthreads();
    int r = blockIdx.x * 256 + threadIdx.x;
    const u16x8* hp = (const u16x8*)(h1 + (size_t)r * 256);
    float acc[11];
#pragma unroll
    for (int j = 0; j < 11; j++) acc[j] = lb[j];
    for (int kc = 0; kc < 32; ++kc) {
        u16x8 hv = hp[kc];
        float hf[8];
#pragma unroll
        for (int x = 0; x < 8; x++) hf[x] = bf2f(hv[x]);
#pragma unroll
        for (int x = 0; x < 8; x++)
#pragma unroll
            for (int j = 0; j < 11; j++) acc[j] = fmaf(hf[x], w[j * 256 + kc * 8 + x], acc[j]);
    }
    int b = r >> 9, t = r & 511;
    float* o = em + ((size_t)t * 64 + b) * 16;
#pragma unroll
    for (int j = 0; j < 11; j++) o[j] = acc[j];
}

// ---------- CRF ----------
__global__ __launch_bounds__(64) void crf_kernel(const float* __restrict__ em,
                                                 const int* __restrict__ tags,
                                                 const float* __restrict__ start_trans,
                                                 const float* __restrict__ end_trans,
                                                 const float* __restrict__ trans,
                                                 float* __restrict__ pb) {
    const int lane = threadIdx.x;
    const int seg = lane >> 4, kp = lane & 15;
    const int kpc = kp < 11 ? kp : 10;
    const int b = blockIdx.x * 4 + seg;
    const int* tg = tags + (size_t)b * 512;
    float num = 0.f;
    for (int t = kp; t < 512; t += 16) {
        int cur = tg[t];
        float e = em[((size_t)t * 64 + b) * 16 + cur];
        float tr = (t == 0) ? start_trans[cur] : trans[tg[t - 1] * 11 + cur];
        num += e + tr;
    }
#pragma unroll
    for (int off = 8; off >= 1; off >>= 1) num += __shfl_down(num, off, 16);
    float trcol[11];
#pragma unroll
    for (int k = 0; k < 11; k++) trcol[k] = trans[k * 11 + kpc];
    float s = start_trans[kpc] + em[(size_t)b * 16 + kpc];
    for (int t = 1; t < 512; ++t) {
        float v[11], m = -1e30f;
#pragma unroll
        for (int k = 0; k < 11; k++) {
            v[k] = __shfl(s, k, 16) + trcol[k];
            m = fmaxf(m, v[k]);
        }
        float sum = 0.f;
#pragma unroll
        for (int k = 0; k < 11; k++) sum += __expf(v[k] - m);
        s = m + __logf(sum) + em[((size_t)t * 64 + b) * 16 + kpc];
    }
    float u = s + end_trans[kpc];
    float m2 = -1e30f, vv[11];
#pragma unroll
    for (int k = 0; k < 11; k++) {
        vv[k] = __shfl(u, k, 16);
        m2 = fmaxf(m2, vv[k]);
    }
    float s2 = 0.f;
#pragma unroll
    for (int k = 0; k < 11; k++) s2 += __expf(vv[k] - m2);
    float den = m2 + __logf(s2);
    if (kp == 0) {
        float numt = num + end_trans[tg[511]];
        pb[b] = numt - den;
    }
}

__global__ __launch_bounds__(64) void final_kernel(const float* __restrict__ pb, float* __restrict__ out) {
    float v = pb[threadIdx.x];
#pragma unroll
    for (int off = 32; off >= 1; off >>= 1) v += __shfl_down(v, off, 64);
    if (threadIdx.x == 0) out[0] = -(v / 64.f);
}

// ---------- launch ----------
extern "C" void kernel_launch(void* const* d_in, const int* in_sizes, int n_in,
                              void* d_out, int out_size, void* d_ws, size_t ws_size,
                              hipStream_t stream) {
    const float* embeds = (const float*)d_in[0];
    const int* tags = (const int*)d_in[1];
    const float* wih0f = (const float*)d_in[3];
    const float* whh0f = (const float*)d_in[4];
    const float* bih0f = (const float*)d_in[5];
    const float* bhh0f = (const float*)d_in[6];
    const float* wih0r = (const float*)d_in[7];
    const float* whh0r = (const float*)d_in[8];
    const float* bih0r = (const float*)d_in[9];
    const float* bhh0r = (const float*)d_in[10];
    const float* wih1f = (const float*)d_in[11];
    const float* whh1f = (const float*)d_in[12];
    const float* bih1f = (const float*)d_in[13];
    const float* bhh1f = (const float*)d_in[14];
    const float* wih1r = (const float*)d_in[15];
    const float* whh1r = (const float*)d_in[16];
    const float* bih1r = (const float*)d_in[17];
    const float* bhh1r = (const float*)d_in[18];
    const float* lw = (const float*)d_in[19];
    const float* lb = (const float*)d_in[20];
    const float* st = (const float*)d_in[21];
    const float* et = (const float*)d_in[22];
    const float* tr = (const float*)d_in[23];
    float* out = (float*)d_out;

    char* ws = (char*)d_ws;
    u16* xproj = (u16*)(ws + 0);            // 64MB
    u16* h0 = (u16*)(ws + 67108864);        // 16MB
    u16* h1 = (u16*)(ws + 83886080);        // 16MB
    float* em = (float*)(ws + 100663296);   // 2MB
    u16* w0c = (u16*)(ws + 102760448);
    u16* w1c = (u16*)(ws + 104333312);
    float* pb = (float*)(ws + 104857600);

    convw_kernel<<<3072, 256, 0, stream>>>(wih0f, wih0r, w0c, 512, 768);
    convw_kernel<<<1024, 256, 0, stream>>>(wih1f, wih1r, w1c, 512, 256);
    gemm_bf16_bt<true><<<dim3(8, 256), 256, 0, stream>>>(embeds, w0c, xproj, 32768, 1024, 768);
    lstm_mfma<<<dim3(32, 2), 256, 0, stream>>>(xproj, whh0f, whh0r, bih0f, bhh0f, bih0r, bhh0r, h0);
    gemm_bf16_bt<false><<<dim3(8, 256), 256, 0, stream>>>(h0, w1c, xproj, 32768, 1024, 256);
    lstm_mfma<<<dim3(32, 2), 256, 0, stream>>>(xproj, whh1f, whh1r, bih1f, bhh1f, bih1r, bhh1r, h1);
    em_kernel<<<128, 256, 0, stream>>>(h1, lw, lb, em);
    crf_kernel<<<16, 64, 0, stream>>>(em, tags, st, et, tr, pb);
    final_kernel<<<1, 64, 0, stream>>>(pb, out);
}